// Round 3
// baseline (610.303 us; speedup 1.0000x reference)
//
#include <hip/hip_runtime.h>
#include <hip/hip_bf16.h>
#include <math.h>

#define NN 2048
#define TT 1024
#define CC 24
#define MAXP 256

// ws layout (bytes):
//   pcls  : float[2048]  @ 0
//   pearl : float[2048]  @ 8192
//   tfin  : int[2048]    @ 16384
//   clsA  : int[2048]    @ 24576
//   vA    : float[2048]  @ 32768
//   rankA : int[2048]    @ 40960
//   sizeA : int[2048]    @ 49152
//   pprox : float[8]     @ 57344

// ---------------- K1: classification + earliness partial sums ----------------
__global__ __launch_bounds__(256) void k_main(const float* __restrict__ logp,
                                              const float* __restrict__ tlft,
                                              const int* __restrict__ yt,
                                              float* __restrict__ pcls,
                                              float* __restrict__ pearl) {
    const float invT = 1.0f / (float)TT;
    float s_cls = 0.0f, s_earl = 0.0f;
    const int total = NN * TT;
    const int stride = gridDim.x * blockDim.x;
    for (int idx = blockIdx.x * blockDim.x + threadIdx.x; idx < total; idx += stride) {
        int y = yt[idx];
        float lp = logp[(size_t)idx * CC + y];
        float tl = tlft[idx];
        int t = idx & (TT - 1);
        s_cls += -lp;
        s_earl += expf(lp) * (1.0f - (float)t * invT) * (1.0f - tl * invT);
    }
    // wave reduce (64 lanes)
    for (int off = 32; off; off >>= 1) {
        s_cls  += __shfl_down(s_cls,  off);
        s_earl += __shfl_down(s_earl, off);
    }
    __shared__ float l1[4], l2[4];
    int wid = threadIdx.x >> 6, lane = threadIdx.x & 63;
    if (lane == 0) { l1[wid] = s_cls; l2[wid] = s_earl; }
    __syncthreads();
    if (threadIdx.x == 0) {
        float a = 0.f, b = 0.f;
        for (int w = 0; w < 4; ++w) { a += l1[w]; b += l2[w]; }
        pcls[blockIdx.x] = a;
        pearl[blockIdx.x] = b;
    }
}

// ---------------- K2: per-row t_final, cls, v ----------------
__global__ __launch_bounds__(64) void k_tfinal(const float* __restrict__ logp,
                                               const float* __restrict__ tlft,
                                               const int* __restrict__ yt,
                                               int* __restrict__ tfin,
                                               int* __restrict__ clsA,
                                               float* __restrict__ vA) {
    int n = blockIdx.x;
    int lane = threadIdx.x;
    const float* row = tlft + (size_t)n * TT;
    int m = TT;  // "not found"
    for (int t = lane; t < TT; t += 64)
        if (row[t] <= 0.0f && t < m) m = t;
    for (int off = 32; off; off >>= 1) {
        int o = __shfl_down(m, off);
        if (o < m) m = o;
    }
    if (lane == 0) {
        if (m == TT) m = 0;  // argmax of all-False boolean -> 0
        int c = yt[(size_t)n * TT];           // y_true[n, 0]
        float v = expf(logp[((size_t)n * TT + m) * CC + c]);
        tfin[n] = m;
        clsA[n] = c;
        vA[n]   = v;
    }
}

// ---------------- K3: rank (count of same-class before n) + class size ----------------
__global__ __launch_bounds__(256) void k_rank(const int* __restrict__ clsA,
                                              int* __restrict__ rankA,
                                              int* __restrict__ sizeA) {
    __shared__ int sc[NN];
    for (int i = threadIdx.x; i < NN; i += 256) sc[i] = clsA[i];
    __syncthreads();
    int n = blockIdx.x * 256 + threadIdx.x;
    int c = sc[n];
    int r = 0, s = 0;
    for (int m = 0; m < NN; ++m) {
        int same = (sc[m] == c) ? 1 : 0;
        s += same;
        r += (same && (m < n)) ? 1 : 0;
    }
    rankA[n] = r;   // #m<n with same class
    sizeA[n] = s;
}

// ---------------- K4: proximity pair sum ----------------
__global__ __launch_bounds__(256) void k_prox(const int* __restrict__ clsA,
                                              const int* __restrict__ rankA,
                                              const int* __restrict__ sizeA,
                                              const int* __restrict__ tfin,
                                              const float* __restrict__ vA,
                                              float* __restrict__ pprox) {
    __shared__ int scls[NN];
    __shared__ int srank[NN];
    __shared__ int stf[NN];
    __shared__ float sv[NN];
    for (int i = threadIdx.x; i < NN; i += 256) {
        scls[i] = clsA[i]; srank[i] = rankA[i]; stf[i] = tfin[i]; sv[i] = vA[i];
    }
    __syncthreads();
    int i = blockIdx.x * 256 + threadIdx.x;
    int ci = scls[i];
    int a  = srank[i];
    int S  = sizeA[i];
    int ti = stf[i];
    float vi = sv[i];
    const float invT = 1.0f / (float)TT;
    float acc = 0.0f;
    for (int j = 0; j < NN; ++j) {
        if (scls[j] == ci) {
            int b = srank[j];
            if (b > a) {
                int combo = a * S - (a * (a + 1)) / 2 + (b - a - 1);
                if (combo < MAXP) {
                    float dtf = (float)(ti - stf[j]) * invT;
                    acc += vi * sv[j] * dtf * dtf;
                }
            }
        }
    }
    // block reduce
    for (int off = 32; off; off >>= 1) acc += __shfl_down(acc, off);
    __shared__ float lp[4];
    int wid = threadIdx.x >> 6, lane = threadIdx.x & 63;
    if (lane == 0) lp[wid] = acc;
    __syncthreads();
    if (threadIdx.x == 0) {
        float s = 0.f;
        for (int w = 0; w < 4; ++w) s += lp[w];
        pprox[blockIdx.x] = s;
    }
}

// ---------------- K5: final deterministic reduction (double) ----------------
__global__ __launch_bounds__(256) void k_final(const float* __restrict__ pcls,
                                               const float* __restrict__ pearl,
                                               const float* __restrict__ pprox,
                                               float* __restrict__ out) {
    double c = 0.0, e = 0.0;
    for (int i = threadIdx.x; i < 2048; i += 256) { c += (double)pcls[i]; e += (double)pearl[i]; }
    for (int off = 32; off; off >>= 1) {
        c += __shfl_down(c, off);
        e += __shfl_down(e, off);
    }
    __shared__ double lc[4], le[4];
    int wid = threadIdx.x >> 6, lane = threadIdx.x & 63;
    if (lane == 0) { lc[wid] = c; le[wid] = e; }
    __syncthreads();
    if (threadIdx.x == 0) {
        double cs = 0.0, es = 0.0;
        for (int w = 0; w < 4; ++w) { cs += lc[w]; es += le[w]; }
        double p = 0.0;
        for (int i = 0; i < 8; ++i) p += (double)pprox[i];
        double loss = (cs / (double)NN) * (1.0 / 3.0)
                    - (es / (double)NN) * (1.0 / 3.0)
                    - p * (1.0 / 3.0);
        out[0] = (float)loss;
    }
}

extern "C" void kernel_launch(void* const* d_in, const int* in_sizes, int n_in,
                              void* d_out, int out_size, void* d_ws, size_t ws_size,
                              hipStream_t stream) {
    const float* logp = (const float*)d_in[0];
    const float* tlft = (const float*)d_in[1];
    const int*   yt   = (const int*)d_in[2];
    float* out = (float*)d_out;

    char* ws = (char*)d_ws;
    float* pcls  = (float*)(ws + 0);
    float* pearl = (float*)(ws + 8192);
    int*   tfin  = (int*)  (ws + 16384);
    int*   clsA  = (int*)  (ws + 24576);
    float* vA    = (float*)(ws + 32768);
    int*   rankA = (int*)  (ws + 40960);
    int*   sizeA = (int*)  (ws + 49152);
    float* pprox = (float*)(ws + 57344);

    k_main  <<<2048, 256, 0, stream>>>(logp, tlft, yt, pcls, pearl);
    k_tfinal<<<2048,  64, 0, stream>>>(logp, tlft, yt, tfin, clsA, vA);
    k_rank  <<<   8, 256, 0, stream>>>(clsA, rankA, sizeA);
    k_prox  <<<   8, 256, 0, stream>>>(clsA, rankA, sizeA, tfin, vA, pprox);
    k_final <<<   1, 256, 0, stream>>>(pcls, pearl, pprox, out);
}

// Round 4
// 300.666 us; speedup vs baseline: 2.0298x; 2.0298x over previous
//
#include <hip/hip_runtime.h>
#include <hip/hip_bf16.h>
#include <math.h>

#define NN 2048
#define TT 1024
#define CC 24
#define MAXP 256

// ws layout (bytes):
//   pcls  : float[2048]  @ 0
//   pearl : float[2048]  @ 8192
//   tfin  : int[2048]    @ 16384
//   clsA  : int[2048]    @ 24576
//   vA    : float[2048]  @ 32768
//   pprox : float[24]    @ 40960

// ---------------- K1: classification + earliness partial sums ----------------
__global__ __launch_bounds__(256) void k_main(const float* __restrict__ logp,
                                              const float* __restrict__ tlft,
                                              const int* __restrict__ yt,
                                              float* __restrict__ pcls,
                                              float* __restrict__ pearl) {
    const float invT = 1.0f / (float)TT;
    float s_cls = 0.0f, s_earl = 0.0f;
    const int total = NN * TT;
    const int stride = gridDim.x * blockDim.x;
    for (int idx = blockIdx.x * blockDim.x + threadIdx.x; idx < total; idx += stride) {
        int y = yt[idx];
        float lp = logp[(size_t)idx * CC + y];
        float tl = tlft[idx];
        int t = idx & (TT - 1);
        s_cls += -lp;
        s_earl += expf(lp) * (1.0f - (float)t * invT) * (1.0f - tl * invT);
    }
    for (int off = 32; off; off >>= 1) {
        s_cls  += __shfl_down(s_cls,  off);
        s_earl += __shfl_down(s_earl, off);
    }
    __shared__ float l1[4], l2[4];
    int wid = threadIdx.x >> 6, lane = threadIdx.x & 63;
    if (lane == 0) { l1[wid] = s_cls; l2[wid] = s_earl; }
    __syncthreads();
    if (threadIdx.x == 0) {
        float a = 0.f, b = 0.f;
        for (int w = 0; w < 4; ++w) { a += l1[w]; b += l2[w]; }
        pcls[blockIdx.x] = a;
        pearl[blockIdx.x] = b;
    }
}

// ---------------- K2: per-row t_final, cls, v ----------------
__global__ __launch_bounds__(64) void k_tfinal(const float* __restrict__ logp,
                                               const float* __restrict__ tlft,
                                               const int* __restrict__ yt,
                                               int* __restrict__ tfin,
                                               int* __restrict__ clsA,
                                               float* __restrict__ vA) {
    int n = blockIdx.x;
    int lane = threadIdx.x;
    const float* row = tlft + (size_t)n * TT;
    int m = TT;  // "not found"
    for (int t = lane; t < TT; t += 64)
        if (row[t] <= 0.0f && t < m) m = t;
    for (int off = 32; off; off >>= 1) {
        int o = __shfl_down(m, off);
        if (o < m) m = o;
    }
    if (lane == 0) {
        if (m == TT) m = 0;  // argmax of all-False boolean -> 0
        int c = yt[(size_t)n * TT];           // y_true[n, 0]
        float v = expf(logp[((size_t)n * TT + m) * CC + c]);
        tfin[n] = m;
        clsA[n] = c;
        vA[n]   = v;
    }
}

// ---------------- K3: per-class proximity (rank = order of appearance) ----------------
// One block per class c. Stable-compact members of class c into LDS (position
// in the list == rank), then evaluate only combos 0..min(MAXP, S(S-1)/2)-1.
__global__ __launch_bounds__(256) void k_prox2(const int* __restrict__ clsA,
                                               const int* __restrict__ tfin,
                                               const float* __restrict__ vA,
                                               float* __restrict__ pprox) {
    __shared__ int   s_tf[NN];
    __shared__ float s_v[NN];
    __shared__ int   s_cnt[256];
    __shared__ int   s_off[257];
    const int c = blockIdx.x;
    const int tid = threadIdx.x;
    const int base = tid * 8;   // 256 threads x 8 = 2048

    int flags[8];
    int cnt = 0;
#pragma unroll
    for (int k = 0; k < 8; ++k) {
        int match = (clsA[base + k] == c) ? 1 : 0;
        flags[k] = match;
        cnt += match;
    }
    s_cnt[tid] = cnt;
    __syncthreads();
    if (tid == 0) {
        int run = 0;
        for (int i = 0; i < 256; ++i) { s_off[i] = run; run += s_cnt[i]; }
        s_off[256] = run;
    }
    __syncthreads();
    int off = s_off[tid];
#pragma unroll
    for (int k = 0; k < 8; ++k) {
        if (flags[k]) {
            int n = base + k;
            s_tf[off] = tfin[n];
            s_v[off]  = vA[n];
            ++off;
        }
    }
    __syncthreads();

    const int S = s_off[256];
    const long long totalPairs = (long long)S * (S - 1) / 2;
    const int lim = (int)(totalPairs < MAXP ? totalPairs : MAXP);
    const float invT = 1.0f / (float)TT;
    float acc = 0.0f;
    for (int combo = tid; combo < lim; combo += 256) {
        // invert combo -> (a,b): base_a = sum_{k<a}(S-1-k); b = a+1+(combo-base_a)
        int a = 0, b0 = 0;
        for (;;) {
            int cA = S - 1 - a;          // #pairs with this a
            if (combo < b0 + cA) break;
            b0 += cA; ++a;
        }
        int b = a + 1 + (combo - b0);
        float dtf = (float)(s_tf[a] - s_tf[b]) * invT;
        acc += s_v[a] * s_v[b] * dtf * dtf;
    }
    for (int o = 32; o; o >>= 1) acc += __shfl_down(acc, o);
    __shared__ float lp[4];
    int wid = tid >> 6, lane = tid & 63;
    if (lane == 0) lp[wid] = acc;
    __syncthreads();
    if (tid == 0) {
        float s = 0.f;
        for (int w = 0; w < 4; ++w) s += lp[w];
        pprox[blockIdx.x] = s;
    }
}

// ---------------- K4: final deterministic reduction (double) ----------------
__global__ __launch_bounds__(256) void k_final(const float* __restrict__ pcls,
                                               const float* __restrict__ pearl,
                                               const float* __restrict__ pprox,
                                               float* __restrict__ out) {
    double c = 0.0, e = 0.0;
    for (int i = threadIdx.x; i < 2048; i += 256) { c += (double)pcls[i]; e += (double)pearl[i]; }
    for (int off = 32; off; off >>= 1) {
        c += __shfl_down(c, off);
        e += __shfl_down(e, off);
    }
    __shared__ double lc[4], le[4];
    int wid = threadIdx.x >> 6, lane = threadIdx.x & 63;
    if (lane == 0) { lc[wid] = c; le[wid] = e; }
    __syncthreads();
    if (threadIdx.x == 0) {
        double cs = 0.0, es = 0.0;
        for (int w = 0; w < 4; ++w) { cs += lc[w]; es += le[w]; }
        double p = 0.0;
        for (int i = 0; i < CC; ++i) p += (double)pprox[i];
        double loss = (cs / (double)NN) * (1.0 / 3.0)
                    - (es / (double)NN) * (1.0 / 3.0)
                    - p * (1.0 / 3.0);
        out[0] = (float)loss;
    }
}

extern "C" void kernel_launch(void* const* d_in, const int* in_sizes, int n_in,
                              void* d_out, int out_size, void* d_ws, size_t ws_size,
                              hipStream_t stream) {
    const float* logp = (const float*)d_in[0];
    const float* tlft = (const float*)d_in[1];
    const int*   yt   = (const int*)d_in[2];
    float* out = (float*)d_out;

    char* ws = (char*)d_ws;
    float* pcls  = (float*)(ws + 0);
    float* pearl = (float*)(ws + 8192);
    int*   tfin  = (int*)  (ws + 16384);
    int*   clsA  = (int*)  (ws + 24576);
    float* vA    = (float*)(ws + 32768);
    float* pprox = (float*)(ws + 40960);

    k_main  <<<2048, 256, 0, stream>>>(logp, tlft, yt, pcls, pearl);
    k_tfinal<<<2048,  64, 0, stream>>>(logp, tlft, yt, tfin, clsA, vA);
    k_prox2 <<<  CC, 256, 0, stream>>>(clsA, tfin, vA, pprox);
    k_final <<<   1, 256, 0, stream>>>(pcls, pearl, pprox, out);
}

// Round 9
// 297.320 us; speedup vs baseline: 2.0527x; 1.0113x over previous
//
#include <hip/hip_runtime.h>
#include <hip/hip_bf16.h>
#include <math.h>

#define NN 2048
#define TT 1024
#define CC 24
#define MAXP 256

// ws layout (bytes):
//   pcls  : float[2048]  @ 0
//   pearl : float[2048]  @ 8192
//   tfin  : int[2048]    @ 16384
//   clsA  : int[2048]    @ 24576
//   vA    : float[2048]  @ 32768

// ---------------- K1: per-row fused pass ----------------
// One block per row n. Computes:
//   pcls[n]  = sum_t -logp[n,t,y[n,t]]
//   pearl[n] = sum_t exp(logp_true)*(1-t/T)*(1-tl/T)
//   tfin[n]  = first t with tlft[n,t] <= 0 (0 if none)
//   clsA[n]  = y[n,0];  vA[n] = exp(logp[n,tfin,cls])
__global__ __launch_bounds__(256) void k_fused(const float* __restrict__ logp,
                                               const float* __restrict__ tlft,
                                               const int* __restrict__ yt,
                                               float* __restrict__ pcls,
                                               float* __restrict__ pearl,
                                               int* __restrict__ tfin,
                                               int* __restrict__ clsA,
                                               float* __restrict__ vA) {
    const int n = blockIdx.x;
    const int tid = threadIdx.x;
    const float invT = 1.0f / (float)TT;
    const size_t rowbase = (size_t)n * TT;

    float s_cls = 0.0f, s_earl = 0.0f;
    int m = TT;
#pragma unroll
    for (int k = 0; k < 4; ++k) {
        int t = tid + k * 256;
        size_t idx = rowbase + t;
        int y = yt[idx];
        float tl = tlft[idx];
        float lp = logp[idx * CC + y];
        s_cls -= lp;
        s_earl += expf(lp) * (1.0f - (float)t * invT) * (1.0f - tl * invT);
        if (tl <= 0.0f && t < m) m = t;
    }
    for (int off = 32; off; off >>= 1) {
        s_cls  += __shfl_down(s_cls,  off);
        s_earl += __shfl_down(s_earl, off);
        int o = __shfl_down(m, off);
        if (o < m) m = o;
    }
    __shared__ float l1[4], l2[4];
    __shared__ int   lm[4];
    int wid = tid >> 6, lane = tid & 63;
    if (lane == 0) { l1[wid] = s_cls; l2[wid] = s_earl; lm[wid] = m; }
    __syncthreads();
    if (tid == 0) {
        float a = 0.f, b = 0.f; int mm = TT;
        for (int w = 0; w < 4; ++w) {
            a += l1[w]; b += l2[w];
            if (lm[w] < mm) mm = lm[w];
        }
        if (mm == TT) mm = 0;  // argmax of all-False -> 0
        int c = yt[rowbase];   // y_true[n, 0]
        pcls[n]  = a;
        pearl[n] = b;
        tfin[n]  = mm;
        clsA[n]  = c;
        vA[n]    = expf(logp[(rowbase + mm) * CC + c]);
    }
}

// ---------------- K2: tail (single block, 1024 threads = 16 waves) ----------------
// Phase A: deterministic reduce of pcls/pearl (2048 each) in double.
// Phase B: per-class proximity. Wave w owns classes {w, w+16}: ballot-based
//          stable compaction (list position == rank), then enumerate only
//          combos 0..min(MAXP, S(S-1)/2)-1. Per-class partials summed by
//          thread 0 in double -> fully deterministic.
__global__ __launch_bounds__(1024) void k_tail(const float* __restrict__ pcls,
                                               const float* __restrict__ pearl,
                                               const int* __restrict__ clsA,
                                               const int* __restrict__ tfin,
                                               const float* __restrict__ vA,
                                               float* __restrict__ out) {
    __shared__ int    s_cls[NN];
    __shared__ int    s_mtf[NN];
    __shared__ float  s_mv[NN];
    __shared__ int    s_csize[CC];
    __shared__ int    s_coff[CC];
    __shared__ float  s_ppart[CC];
    __shared__ double lc[16], le[16];

    const int tid  = threadIdx.x;
    const int wid  = tid >> 6;
    const int lane = tid & 63;

    // ---- Phase A: pcls/pearl reduction ----
    double c = (double)pcls[tid] + (double)pcls[tid + 1024];
    double e = (double)pearl[tid] + (double)pearl[tid + 1024];
    for (int off = 32; off; off >>= 1) {
        c += __shfl_down(c, off);
        e += __shfl_down(e, off);
    }
    if (lane == 0) { lc[wid] = c; le[wid] = e; }

    // ---- Phase B: stage clsA ----
    s_cls[tid] = clsA[tid];
    s_cls[tid + 1024] = clsA[tid + 1024];
    if (tid < CC) s_ppart[tid] = 0.0f;
    __syncthreads();

    // pass 1: per-class counts (wave w -> classes w, w+16)
    for (int cc = wid; cc < CC; cc += 16) {
        int cnt = 0;
        for (int chunk = 0; chunk < NN / 64; ++chunk) {
            bool f = (s_cls[chunk * 64 + lane] == cc);
            unsigned long long mask = __ballot(f);
            cnt += __popcll(mask);
        }
        if (lane == 0) s_csize[cc] = cnt;
    }
    __syncthreads();
    if (tid == 0) {
        int run = 0;
        for (int i = 0; i < CC; ++i) { s_coff[i] = run; run += s_csize[i]; }
    }
    __syncthreads();

    // pass 2: stable scatter + pair enumeration
    const float invT = 1.0f / (float)TT;
    for (int cc = wid; cc < CC; cc += 16) {
        int base = s_coff[cc];
        const int S = s_csize[cc];
        for (int chunk = 0; chunk < NN / 64; ++chunk) {
            int nidx = chunk * 64 + lane;
            bool f = (s_cls[nidx] == cc);
            unsigned long long mask = __ballot(f);
            if (f) {
                int pos = base + __popcll(mask & ((1ULL << lane) - 1ULL));
                s_mtf[pos] = tfin[nidx];
                s_mv[pos]  = vA[nidx];
            }
            base += __popcll(mask);
        }
        // enumerate pairs (same wave that wrote the list; no barrier needed)
        long long totalPairs = (long long)S * (S - 1) / 2;
        int lim = (int)(totalPairs < MAXP ? totalPairs : MAXP);
        int cbase = s_coff[cc];
        float acc = 0.0f;
        for (int combo = lane; combo < lim; combo += 64) {
            int a = 0, b0 = 0;
            for (;;) {
                int cA = S - 1 - a;
                if (combo < b0 + cA) break;
                b0 += cA; ++a;
            }
            int b = a + 1 + (combo - b0);
            float dtf = (float)(s_mtf[cbase + a] - s_mtf[cbase + b]) * invT;
            acc += s_mv[cbase + a] * s_mv[cbase + b] * dtf * dtf;
        }
        for (int off = 32; off; off >>= 1) acc += __shfl_down(acc, off);
        if (lane == 0) s_ppart[cc] = acc;
    }
    __syncthreads();

    // ---- final combine (deterministic, double) ----
    if (tid == 0) {
        double cs = 0.0, es = 0.0;
        for (int w = 0; w < 16; ++w) { cs += lc[w]; es += le[w]; }
        double p = 0.0;
        for (int i = 0; i < CC; ++i) p += (double)s_ppart[i];
        double loss = (cs / (double)NN) * (1.0 / 3.0)
                    - (es / (double)NN) * (1.0 / 3.0)
                    - p * (1.0 / 3.0);
        out[0] = (float)loss;
    }
}

extern "C" void kernel_launch(void* const* d_in, const int* in_sizes, int n_in,
                              void* d_out, int out_size, void* d_ws, size_t ws_size,
                              hipStream_t stream) {
    const float* logp = (const float*)d_in[0];
    const float* tlft = (const float*)d_in[1];
    const int*   yt   = (const int*)d_in[2];
    float* out = (float*)d_out;

    char* ws = (char*)d_ws;
    float* pcls  = (float*)(ws + 0);
    float* pearl = (float*)(ws + 8192);
    int*   tfin  = (int*)  (ws + 16384);
    int*   clsA  = (int*)  (ws + 24576);
    float* vA    = (float*)(ws + 32768);

    k_fused<<<NN, 256, 0, stream>>>(logp, tlft, yt, pcls, pearl, tfin, clsA, vA);
    k_tail <<< 1, 1024, 0, stream>>>(pcls, pearl, clsA, tfin, vA, out);
}